// Round 2
// baseline (367.701 us; speedup 1.0000x reference)
//
#include <hip/hip_runtime.h>
#include <cstdint>
#include <cstddef>

// ---------------------------------------------------------------------------
// QuantizedLinear: out = x @ W^T + bias, W/bias affine-dequant from int16-range
// B=8192, IN=4096, OUT=4096. Strategy: dequant to bf16 in ws, then a 256x256
// deep-pipelined MFMA GEMM (8 waves, 4 K-half LDS slots, counted vmcnt(8),
// setprio around MFMA clusters, XCD-swizzled blockIdx).
// ---------------------------------------------------------------------------

#define B_DIM  8192
#define IN_DIM 4096
#define OUT_DIM 4096

typedef short    bf16x8 __attribute__((ext_vector_type(8)));
typedef float    f32x4  __attribute__((ext_vector_type(4)));
typedef uint16_t u16x8  __attribute__((ext_vector_type(8)));

// round-to-nearest-even fp32 -> bf16
__device__ __forceinline__ uint16_t f2bf(float f) {
  uint32_t u = __builtin_bit_cast(uint32_t, f);
  u += 0x7FFFu + ((u >> 16) & 1u);
  return (uint16_t)(u >> 16);
}

__device__ __forceinline__ void gload_lds16(const void* g, void* l) {
  __builtin_amdgcn_global_load_lds(
      (const __attribute__((address_space(1))) unsigned int*)g,
      (__attribute__((address_space(3))) unsigned int*)l,
      16, 0, 0);
}

// ---------------- prologue: conversions ----------------

__global__ void cvt_x_kernel(const float* __restrict__ x,
                             uint16_t* __restrict__ o) {
  size_t i = (size_t)blockIdx.x * blockDim.x + threadIdx.x;  // 8 elems each
  const float4* xv = (const float4*)x;
  float4 a = xv[i * 2], b = xv[i * 2 + 1];
  u16x8 r;
  r[0] = f2bf(a.x); r[1] = f2bf(a.y); r[2] = f2bf(a.z); r[3] = f2bf(a.w);
  r[4] = f2bf(b.x); r[5] = f2bf(b.y); r[6] = f2bf(b.z); r[7] = f2bf(b.w);
  ((u16x8*)o)[i] = r;
}

__global__ void cvt_w_kernel(const int* __restrict__ q,
                             uint16_t* __restrict__ o,
                             const float* __restrict__ sp,
                             const float* __restrict__ wminp) {
  size_t i = (size_t)blockIdx.x * blockDim.x + threadIdx.x;  // 8 elems each
  float s = *sp, wmin = *wminp;
  const int4* qv = (const int4*)q;
  int4 a = qv[i * 2], b = qv[i * 2 + 1];
  u16x8 r;
  r[0] = f2bf(fmaf((float)a.x + 32768.0f, s, wmin));
  r[1] = f2bf(fmaf((float)a.y + 32768.0f, s, wmin));
  r[2] = f2bf(fmaf((float)a.z + 32768.0f, s, wmin));
  r[3] = f2bf(fmaf((float)a.w + 32768.0f, s, wmin));
  r[4] = f2bf(fmaf((float)b.x + 32768.0f, s, wmin));
  r[5] = f2bf(fmaf((float)b.y + 32768.0f, s, wmin));
  r[6] = f2bf(fmaf((float)b.z + 32768.0f, s, wmin));
  r[7] = f2bf(fmaf((float)b.w + 32768.0f, s, wmin));
  ((u16x8*)o)[i] = r;
}

__global__ void cvt_bias_kernel(const int* __restrict__ qb,
                                float* __restrict__ o,
                                const float* __restrict__ bsp,
                                const float* __restrict__ bminp) {
  int i = blockIdx.x * blockDim.x + threadIdx.x;
  if (i < OUT_DIM)
    o[i] = fmaf((float)qb[i] + 32768.0f, *bsp, *bminp);
}

// ---------------- main GEMM: 256x256 tile, 4 K-half slot pipeline ----------
// A = Xbf16 [8192,4096] row-major; Bw = Wbf16 [4096,4096] row-major (NT GEMM).
// 8 waves (wm=wave>>2 in {0,1}: 128 rows; wn=wave&3: 64 cols).
// LDS: 4 slots per operand, slot = [256 rows][32 k] bf16 (16 KiB). 64-B rows
// -> ds_read_b128 fragment reads are bank-even (no swizzle needed) and
// global_load_lds stages linearly. Slot s holds K-half H (H&3==s).
// Phase P=2H+nh consumes K-half H; K-half G is staged at phases 2G-6, 2G-5
// (slot freed at end of phase 2G-7; every wave drains lgkmcnt before the
// phase-end barrier, so restage-after-one-barrier is race-free).
// vmcnt(8) at every odd-phase end => stages >=4 phases old have landed;
// G's first read (phase 2G) is 5-6 phases after its stage. Never vmcnt(0).

__global__ __launch_bounds__(512, 2) void gemm256_kernel(
    const uint16_t* __restrict__ A, const uint16_t* __restrict__ Bw,
    const float* __restrict__ bias, float* __restrict__ C) {
  __shared__ bf16x8 Asl[4][1024];  // 4 x 16 KiB
  __shared__ bf16x8 Bsl[4][1024];  // 4 x 16 KiB

  const int tid  = threadIdx.x;
  const int wave = tid >> 6;
  const int lane = tid & 63;

  // XCD-aware swizzle: nwg=512, 8 XCDs, 64 contiguous per XCD (bijective)
  int bid = blockIdx.x;
  int swz = (bid & 7) * 64 + (bid >> 3);
  const int bm = swz >> 4;          // 32 M-blocks
  const int bn = swz & 15;          // 16 N-blocks
  const int M0 = bm * 256, N0 = bn * 256;

  const int wm = wave >> 2, wn = wave & 3;
  const int l15 = lane & 15, l4 = lane >> 4;

  // stage addressing: issue (G, j): row = j*128 + wave*16 + (lane>>2),
  //                                 col = G*32 + (lane&3)*8
  const uint16_t* aSrc =
      A + (size_t)(M0 + wave * 16 + (lane >> 2)) * IN_DIM + (lane & 3) * 8;
  const uint16_t* bSrc =
      Bw + (size_t)(N0 + wave * 16 + (lane >> 2)) * IN_DIM + (lane & 3) * 8;

  f32x4 acc[8][4];
#pragma unroll
  for (int i = 0; i < 8; ++i)
#pragma unroll
    for (int j = 0; j < 4; ++j) acc[i][j] = (f32x4){0.f, 0.f, 0.f, 0.f};

#define STAGE_A(G, j)                                                       \
  gload_lds16(aSrc + (size_t)(j) * 128 * IN_DIM + (size_t)(G) * 32,         \
              (char*)&Asl[(G) & 3][0] + (j) * 8192 + wave * 1024)
#define STAGE_B(G, j)                                                       \
  gload_lds16(bSrc + (size_t)(j) * 128 * IN_DIM + (size_t)(G) * 32,         \
              (char*)&Bsl[(G) & 3][0] + (j) * 8192 + wave * 1024)

  // prologue: stage K-halves 0,1,2 (12 issues); wait oldest 4 (= H0) landed
  for (int G = 0; G < 3; ++G) {
    STAGE_A(G, 0); STAGE_A(G, 1); STAGE_B(G, 0); STAGE_B(G, 1);
  }
  asm volatile("s_waitcnt vmcnt(8)" ::: "memory");
  __builtin_amdgcn_s_barrier();
  __builtin_amdgcn_sched_barrier(0);

  bf16x8 af[8], b0, b1;

  for (int t = 0; t < 64; ++t) {
    const int s0 = (2 * t) & 3, s1 = (2 * t + 1) & 3;
    const int Ga = 2 * t + 3, Gb = 2 * t + 4;
    const bool pa = (Ga < 128), pb = (Gb < 128);

    // ---- phase (kh=0, nh=0): load all 8 A-frags + B nf 0,1; stage Ga.j0
    {
      const bf16x8* Ap = &Asl[s0][0];
      const bf16x8* Bp = &Bsl[s0][0];
#pragma unroll
      for (int mf = 0; mf < 8; ++mf)
        af[mf] = Ap[(wm * 128 + mf * 16 + l15) * 4 + l4];
      b0 = Bp[(wn * 64 + 0 * 16 + l15) * 4 + l4];
      b1 = Bp[(wn * 64 + 1 * 16 + l15) * 4 + l4];
      if (pa) { STAGE_A(Ga, 0); STAGE_B(Ga, 0); }
      __builtin_amdgcn_s_barrier();
      asm volatile("s_waitcnt lgkmcnt(0)" ::: "memory");
      __builtin_amdgcn_s_setprio(1);
#pragma unroll
      for (int mf = 0; mf < 8; ++mf) {
        acc[mf][0] = __builtin_amdgcn_mfma_f32_16x16x32_bf16(af[mf], b0, acc[mf][0], 0, 0, 0);
        acc[mf][1] = __builtin_amdgcn_mfma_f32_16x16x32_bf16(af[mf], b1, acc[mf][1], 0, 0, 0);
      }
      __builtin_amdgcn_s_setprio(0);
      __builtin_amdgcn_s_barrier();
      __builtin_amdgcn_sched_barrier(0);
    }
    // ---- phase (0,1): reuse af; B nf 2,3; stage Ga.j1; vmcnt checkpoint
    {
      const bf16x8* Bp = &Bsl[s0][0];
      b0 = Bp[(wn * 64 + 2 * 16 + l15) * 4 + l4];
      b1 = Bp[(wn * 64 + 3 * 16 + l15) * 4 + l4];
      if (pa) { STAGE_A(Ga, 1); STAGE_B(Ga, 1); }
      __builtin_amdgcn_s_barrier();
      asm volatile("s_waitcnt lgkmcnt(0)" ::: "memory");
      __builtin_amdgcn_s_setprio(1);
#pragma unroll
      for (int mf = 0; mf < 8; ++mf) {
        acc[mf][2] = __builtin_amdgcn_mfma_f32_16x16x32_bf16(af[mf], b0, acc[mf][2], 0, 0, 0);
        acc[mf][3] = __builtin_amdgcn_mfma_f32_16x16x32_bf16(af[mf], b1, acc[mf][3], 0, 0, 0);
      }
      __builtin_amdgcn_s_setprio(0);
      asm volatile("s_waitcnt vmcnt(8)" ::: "memory");
      __builtin_amdgcn_s_barrier();
      __builtin_amdgcn_sched_barrier(0);
    }
    // ---- phase (1,0): slot s1; stage Gb.j0
    {
      const bf16x8* Ap = &Asl[s1][0];
      const bf16x8* Bp = &Bsl[s1][0];
#pragma unroll
      for (int mf = 0; mf < 8; ++mf)
        af[mf] = Ap[(wm * 128 + mf * 16 + l15) * 4 + l4];
      b0 = Bp[(wn * 64 + 0 * 16 + l15) * 4 + l4];
      b1 = Bp[(wn * 64 + 1 * 16 + l15) * 4 + l4];
      if (pb) { STAGE_A(Gb, 0); STAGE_B(Gb, 0); }
      __builtin_amdgcn_s_barrier();
      asm volatile("s_waitcnt lgkmcnt(0)" ::: "memory");
      __builtin_amdgcn_s_setprio(1);
#pragma unroll
      for (int mf = 0; mf < 8; ++mf) {
        acc[mf][0] = __builtin_amdgcn_mfma_f32_16x16x32_bf16(af[mf], b0, acc[mf][0], 0, 0, 0);
        acc[mf][1] = __builtin_amdgcn_mfma_f32_16x16x32_bf16(af[mf], b1, acc[mf][1], 0, 0, 0);
      }
      __builtin_amdgcn_s_setprio(0);
      __builtin_amdgcn_s_barrier();
      __builtin_amdgcn_sched_barrier(0);
    }
    // ---- phase (1,1): reuse af; stage Gb.j1; vmcnt checkpoint
    {
      const bf16x8* Bp = &Bsl[s1][0];
      b0 = Bp[(wn * 64 + 2 * 16 + l15) * 4 + l4];
      b1 = Bp[(wn * 64 + 3 * 16 + l15) * 4 + l4];
      if (pb) { STAGE_A(Gb, 1); STAGE_B(Gb, 1); }
      __builtin_amdgcn_s_barrier();
      asm volatile("s_waitcnt lgkmcnt(0)" ::: "memory");
      __builtin_amdgcn_s_setprio(1);
#pragma unroll
      for (int mf = 0; mf < 8; ++mf) {
        acc[mf][2] = __builtin_amdgcn_mfma_f32_16x16x32_bf16(af[mf], b0, acc[mf][2], 0, 0, 0);
        acc[mf][3] = __builtin_amdgcn_mfma_f32_16x16x32_bf16(af[mf], b1, acc[mf][3], 0, 0, 0);
      }
      __builtin_amdgcn_s_setprio(0);
      asm volatile("s_waitcnt vmcnt(8)" ::: "memory");
      __builtin_amdgcn_s_barrier();
      __builtin_amdgcn_sched_barrier(0);
    }
  }
#undef STAGE_A
#undef STAGE_B

  // epilogue: C/D frag layout col=lane&15, row=(lane>>4)*4+j
  const int ccol = N0 + wn * 64 + l15;
#pragma unroll
  for (int nf = 0; nf < 4; ++nf) {
    float bv = bias[ccol + nf * 16];
#pragma unroll
    for (int mf = 0; mf < 8; ++mf) {
      const int r0 = M0 + wm * 128 + mf * 16 + l4 * 4;
#pragma unroll
      for (int j = 0; j < 4; ++j)
        C[(size_t)(r0 + j) * OUT_DIM + ccol + nf * 16] = acc[mf][nf][j] + bv;
    }
  }
}

// ---------------- naive fallback (only if ws too small) ----------------
__global__ void naive_ql_kernel(const float* __restrict__ x,
                                const int* __restrict__ qw,
                                const int* __restrict__ qb,
                                const float* sp, const float* wminp,
                                const float* bsp, const float* bminp,
                                float* __restrict__ out) {
  int o = blockIdx.x * blockDim.x + threadIdx.x;
  int b = blockIdx.y;
  float s = *sp, wmin = *wminp;
  const float* xr = x + (size_t)b * IN_DIM;
  const int* wrow = qw + (size_t)o * IN_DIM;
  float acc = 0.f;
  for (int k = 0; k < IN_DIM; ++k)
    acc += xr[k] * fmaf((float)wrow[k] + 32768.0f, s, wmin);
  out[(size_t)b * OUT_DIM + o] =
      acc + fmaf((float)qb[o] + 32768.0f, *bsp, *bminp);
}

// ---------------- launch ----------------
extern "C" void kernel_launch(void* const* d_in, const int* in_sizes, int n_in,
                              void* d_out, int out_size, void* d_ws,
                              size_t ws_size, hipStream_t stream) {
  const float* x      = (const float*)d_in[0];
  const int*   qw     = (const int*)d_in[1];
  const int*   qb     = (const int*)d_in[2];
  const float* scale  = (const float*)d_in[3];
  const float* wmin   = (const float*)d_in[4];
  const float* bscale = (const float*)d_in[5];
  const float* bmin   = (const float*)d_in[6];
  float* out = (float*)d_out;

  const size_t xb_bytes = (size_t)B_DIM * IN_DIM * 2;      // 64 MiB
  const size_t wb_bytes = (size_t)OUT_DIM * IN_DIM * 2;    // 32 MiB
  const size_t bias_bytes = (size_t)OUT_DIM * 4;

  if (ws_size < xb_bytes + wb_bytes + bias_bytes) {
    naive_ql_kernel<<<dim3(OUT_DIM / 256, B_DIM), 256, 0, stream>>>(
        x, qw, qb, scale, wmin, bscale, bmin, out);
    return;
  }

  uint16_t* Xb    = (uint16_t*)d_ws;
  uint16_t* Wb    = (uint16_t*)((char*)d_ws + xb_bytes);
  float*    biasf = (float*)((char*)d_ws + xb_bytes + wb_bytes);

  cvt_x_kernel<<<(B_DIM * (size_t)IN_DIM / 8 + 255) / 256, 256, 0, stream>>>(x, Xb);
  cvt_w_kernel<<<(OUT_DIM * (size_t)IN_DIM / 8 + 255) / 256, 256, 0, stream>>>(
      qw, Wb, scale, wmin);
  cvt_bias_kernel<<<(OUT_DIM + 255) / 256, 256, 0, stream>>>(qb, biasf, bscale,
                                                             bmin);

  gemm256_kernel<<<512, 512, 0, stream>>>(Xb, Wb, biasf, out);
}

// Round 3
// 346.945 us; speedup vs baseline: 1.0598x; 1.0598x over previous
//
#include <hip/hip_runtime.h>
#include <cstdint>
#include <cstddef>

// ---------------------------------------------------------------------------
// QuantizedLinear: out = x @ W^T + bias, W/bias affine-dequant from int16-range
// B=8192, IN=4096, OUT=4096. Dequant to bf16 in ws, then 256x256 deep-pipelined
// MFMA GEMM (8 waves, 4 K-half LDS slots, counted vmcnt(8), setprio, XCD
// swizzle). R3 change: chunk-XOR LDS swizzle (rule #21: pre-swizzled global
// source + swizzled ds_read; LDS dest stays linear) -> conflict-free reads.
// ---------------------------------------------------------------------------

#define B_DIM  8192
#define IN_DIM 4096
#define OUT_DIM 4096

typedef short    bf16x8 __attribute__((ext_vector_type(8)));
typedef float    f32x4  __attribute__((ext_vector_type(4)));
typedef uint16_t u16x8  __attribute__((ext_vector_type(8)));

// round-to-nearest-even fp32 -> bf16
__device__ __forceinline__ uint16_t f2bf(float f) {
  uint32_t u = __builtin_bit_cast(uint32_t, f);
  u += 0x7FFFu + ((u >> 16) & 1u);
  return (uint16_t)(u >> 16);
}

__device__ __forceinline__ void gload_lds16(const void* g, void* l) {
  __builtin_amdgcn_global_load_lds(
      (const __attribute__((address_space(1))) unsigned int*)g,
      (__attribute__((address_space(3))) unsigned int*)l,
      16, 0, 0);
}

// ---------------- prologue: conversions ----------------

__global__ void cvt_x_kernel(const float* __restrict__ x,
                             uint16_t* __restrict__ o) {
  size_t i = (size_t)blockIdx.x * blockDim.x + threadIdx.x;  // 8 elems each
  const float4* xv = (const float4*)x;
  float4 a = xv[i * 2], b = xv[i * 2 + 1];
  u16x8 r;
  r[0] = f2bf(a.x); r[1] = f2bf(a.y); r[2] = f2bf(a.z); r[3] = f2bf(a.w);
  r[4] = f2bf(b.x); r[5] = f2bf(b.y); r[6] = f2bf(b.z); r[7] = f2bf(b.w);
  ((u16x8*)o)[i] = r;
}

__global__ void cvt_w_kernel(const int* __restrict__ q,
                             uint16_t* __restrict__ o,
                             const float* __restrict__ sp,
                             const float* __restrict__ wminp) {
  size_t i = (size_t)blockIdx.x * blockDim.x + threadIdx.x;  // 8 elems each
  float s = *sp, wmin = *wminp;
  const int4* qv = (const int4*)q;
  int4 a = qv[i * 2], b = qv[i * 2 + 1];
  u16x8 r;
  r[0] = f2bf(fmaf((float)a.x + 32768.0f, s, wmin));
  r[1] = f2bf(fmaf((float)a.y + 32768.0f, s, wmin));
  r[2] = f2bf(fmaf((float)a.z + 32768.0f, s, wmin));
  r[3] = f2bf(fmaf((float)a.w + 32768.0f, s, wmin));
  r[4] = f2bf(fmaf((float)b.x + 32768.0f, s, wmin));
  r[5] = f2bf(fmaf((float)b.y + 32768.0f, s, wmin));
  r[6] = f2bf(fmaf((float)b.z + 32768.0f, s, wmin));
  r[7] = f2bf(fmaf((float)b.w + 32768.0f, s, wmin));
  ((u16x8*)o)[i] = r;
}

__global__ void cvt_bias_kernel(const int* __restrict__ qb,
                                float* __restrict__ o,
                                const float* __restrict__ bsp,
                                const float* __restrict__ bminp) {
  int i = blockIdx.x * blockDim.x + threadIdx.x;
  if (i < OUT_DIM)
    o[i] = fmaf((float)qb[i] + 32768.0f, *bsp, *bminp);
}

// ---------------- main GEMM: 256x256 tile, 4 K-half slot pipeline ----------
// LDS slot = [256 rows][32 k] bf16 (64-B rows). SWIZZLE: element (row, chunk)
// [chunk = 16B unit, 0..3] is stored at chunk' = chunk ^ ((row>>1)&3).
//   - read position p = 4*(row&1) + chunk' covers all 8 LDS 16B-slots exactly
//     2x per 16-lane group -> 2 lanes/bank -> conflict-free (m136).
//   - global_load_lds dest stays linear; the permutation is applied to the
//     per-lane GLOBAL source column (involution, same XOR).
// Pipeline: slot s holds K-half H (H&3==s); K-half G staged at phases
// 2G-6/2G-5; vmcnt(8) at odd-phase ends guarantees landing >=4 phases before
// first read. Never vmcnt(0) in the loop.

__global__ __launch_bounds__(512, 2) void gemm256_kernel(
    const uint16_t* __restrict__ A, const uint16_t* __restrict__ Bw,
    const float* __restrict__ bias, float* __restrict__ C) {
  __shared__ bf16x8 Asl[4][1024];  // 4 x 16 KiB
  __shared__ bf16x8 Bsl[4][1024];  // 4 x 16 KiB

  const int tid  = threadIdx.x;
  const int wave = tid >> 6;
  const int lane = tid & 63;

  // XCD-aware swizzle: nwg=512, 8 XCDs, 64 contiguous per XCD (bijective)
  int bid = blockIdx.x;
  int swz = (bid & 7) * 64 + (bid >> 3);
  const int bm = swz >> 4;          // 32 M-blocks
  const int bn = swz & 15;          // 16 N-blocks
  const int M0 = bm * 256, N0 = bn * 256;

  const int wm = wave >> 2, wn = wave & 3;
  const int l15 = lane & 15, l4 = lane >> 4;
  // swizzled k-chunk for all fragment reads (row bits 1,2 == l15 bits 1,2)
  const int swk = l4 ^ ((l15 >> 1) & 3);

  // stage addressing: issue (G, j): row = j*128 + wave*16 + (lane>>2).
  // linear LDS dest receives chunk (lane&3) of row -> fetch global chunk
  // (lane&3) ^ rho(row), rho = (row>>1)&3 = (lane>>3)&3.
  const int schunk = (lane & 3) ^ ((lane >> 3) & 3);
  const uint16_t* aSrc =
      A + (size_t)(M0 + wave * 16 + (lane >> 2)) * IN_DIM + schunk * 8;
  const uint16_t* bSrc =
      Bw + (size_t)(N0 + wave * 16 + (lane >> 2)) * IN_DIM + schunk * 8;

  f32x4 acc[8][4];
#pragma unroll
  for (int i = 0; i < 8; ++i)
#pragma unroll
    for (int j = 0; j < 4; ++j) acc[i][j] = (f32x4){0.f, 0.f, 0.f, 0.f};

#define STAGE_A(G, j)                                                       \
  gload_lds16(aSrc + (size_t)(j) * 128 * IN_DIM + (size_t)(G) * 32,         \
              (char*)&Asl[(G) & 3][0] + (j) * 8192 + wave * 1024)
#define STAGE_B(G, j)                                                       \
  gload_lds16(bSrc + (size_t)(j) * 128 * IN_DIM + (size_t)(G) * 32,         \
              (char*)&Bsl[(G) & 3][0] + (j) * 8192 + wave * 1024)

  // prologue: stage K-halves 0,1,2 (12 issues); wait oldest 4 (= H0) landed
  for (int G = 0; G < 3; ++G) {
    STAGE_A(G, 0); STAGE_A(G, 1); STAGE_B(G, 0); STAGE_B(G, 1);
  }
  asm volatile("s_waitcnt vmcnt(8)" ::: "memory");
  __builtin_amdgcn_s_barrier();
  __builtin_amdgcn_sched_barrier(0);

  bf16x8 af[8], b0, b1;

  for (int t = 0; t < 64; ++t) {
    const int s0 = (2 * t) & 3, s1 = (2 * t + 1) & 3;
    const int Ga = 2 * t + 3, Gb = 2 * t + 4;
    const bool pa = (Ga < 128), pb = (Gb < 128);

    // ---- phase (kh=0, nh=0): load all 8 A-frags + B nf 0,1; stage Ga.j0
    {
      const bf16x8* Ap = &Asl[s0][0];
      const bf16x8* Bp = &Bsl[s0][0];
#pragma unroll
      for (int mf = 0; mf < 8; ++mf)
        af[mf] = Ap[(wm * 128 + mf * 16 + l15) * 4 + swk];
      b0 = Bp[(wn * 64 + 0 * 16 + l15) * 4 + swk];
      b1 = Bp[(wn * 64 + 1 * 16 + l15) * 4 + swk];
      if (pa) { STAGE_A(Ga, 0); STAGE_B(Ga, 0); }
      __builtin_amdgcn_s_barrier();
      asm volatile("s_waitcnt lgkmcnt(0)" ::: "memory");
      __builtin_amdgcn_s_setprio(1);
#pragma unroll
      for (int mf = 0; mf < 8; ++mf) {
        acc[mf][0] = __builtin_amdgcn_mfma_f32_16x16x32_bf16(af[mf], b0, acc[mf][0], 0, 0, 0);
        acc[mf][1] = __builtin_amdgcn_mfma_f32_16x16x32_bf16(af[mf], b1, acc[mf][1], 0, 0, 0);
      }
      __builtin_amdgcn_s_setprio(0);
      __builtin_amdgcn_s_barrier();
      __builtin_amdgcn_sched_barrier(0);
    }
    // ---- phase (0,1): reuse af; B nf 2,3; stage Ga.j1; vmcnt checkpoint
    {
      const bf16x8* Bp = &Bsl[s0][0];
      b0 = Bp[(wn * 64 + 2 * 16 + l15) * 4 + swk];
      b1 = Bp[(wn * 64 + 3 * 16 + l15) * 4 + swk];
      if (pa) { STAGE_A(Ga, 1); STAGE_B(Ga, 1); }
      __builtin_amdgcn_s_barrier();
      asm volatile("s_waitcnt lgkmcnt(0)" ::: "memory");
      __builtin_amdgcn_s_setprio(1);
#pragma unroll
      for (int mf = 0; mf < 8; ++mf) {
        acc[mf][2] = __builtin_amdgcn_mfma_f32_16x16x32_bf16(af[mf], b0, acc[mf][2], 0, 0, 0);
        acc[mf][3] = __builtin_amdgcn_mfma_f32_16x16x32_bf16(af[mf], b1, acc[mf][3], 0, 0, 0);
      }
      __builtin_amdgcn_s_setprio(0);
      asm volatile("s_waitcnt vmcnt(8)" ::: "memory");
      __builtin_amdgcn_s_barrier();
      __builtin_amdgcn_sched_barrier(0);
    }
    // ---- phase (1,0): slot s1; stage Gb.j0
    {
      const bf16x8* Ap = &Asl[s1][0];
      const bf16x8* Bp = &Bsl[s1][0];
#pragma unroll
      for (int mf = 0; mf < 8; ++mf)
        af[mf] = Ap[(wm * 128 + mf * 16 + l15) * 4 + swk];
      b0 = Bp[(wn * 64 + 0 * 16 + l15) * 4 + swk];
      b1 = Bp[(wn * 64 + 1 * 16 + l15) * 4 + swk];
      if (pb) { STAGE_A(Gb, 0); STAGE_B(Gb, 0); }
      __builtin_amdgcn_s_barrier();
      asm volatile("s_waitcnt lgkmcnt(0)" ::: "memory");
      __builtin_amdgcn_s_setprio(1);
#pragma unroll
      for (int mf = 0; mf < 8; ++mf) {
        acc[mf][0] = __builtin_amdgcn_mfma_f32_16x16x32_bf16(af[mf], b0, acc[mf][0], 0, 0, 0);
        acc[mf][1] = __builtin_amdgcn_mfma_f32_16x16x32_bf16(af[mf], b1, acc[mf][1], 0, 0, 0);
      }
      __builtin_amdgcn_s_setprio(0);
      __builtin_amdgcn_s_barrier();
      __builtin_amdgcn_sched_barrier(0);
    }
    // ---- phase (1,1): reuse af; stage Gb.j1; vmcnt checkpoint
    {
      const bf16x8* Bp = &Bsl[s1][0];
      b0 = Bp[(wn * 64 + 2 * 16 + l15) * 4 + swk];
      b1 = Bp[(wn * 64 + 3 * 16 + l15) * 4 + swk];
      if (pb) { STAGE_A(Gb, 1); STAGE_B(Gb, 1); }
      __builtin_amdgcn_s_barrier();
      asm volatile("s_waitcnt lgkmcnt(0)" ::: "memory");
      __builtin_amdgcn_s_setprio(1);
#pragma unroll
      for (int mf = 0; mf < 8; ++mf) {
        acc[mf][2] = __builtin_amdgcn_mfma_f32_16x16x32_bf16(af[mf], b0, acc[mf][2], 0, 0, 0);
        acc[mf][3] = __builtin_amdgcn_mfma_f32_16x16x32_bf16(af[mf], b1, acc[mf][3], 0, 0, 0);
      }
      __builtin_amdgcn_s_setprio(0);
      asm volatile("s_waitcnt vmcnt(8)" ::: "memory");
      __builtin_amdgcn_s_barrier();
      __builtin_amdgcn_sched_barrier(0);
    }
  }
#undef STAGE_A
#undef STAGE_B

  // epilogue: C/D frag layout col=lane&15, row=(lane>>4)*4+j
  const int ccol = N0 + wn * 64 + l15;
#pragma unroll
  for (int nf = 0; nf < 4; ++nf) {
    float bv = bias[ccol + nf * 16];
#pragma unroll
    for (int mf = 0; mf < 8; ++mf) {
      const int r0 = M0 + wm * 128 + mf * 16 + l4 * 4;
#pragma unroll
      for (int j = 0; j < 4; ++j)
        C[(size_t)(r0 + j) * OUT_DIM + ccol + nf * 16] = acc[mf][nf][j] + bv;
    }
  }
}

// ---------------- naive fallback (only if ws too small) ----------------
__global__ void naive_ql_kernel(const float* __restrict__ x,
                                const int* __restrict__ qw,
                                const int* __restrict__ qb,
                                const float* sp, const float* wminp,
                                const float* bsp, const float* bminp,
                                float* __restrict__ out) {
  int o = blockIdx.x * blockDim.x + threadIdx.x;
  int b = blockIdx.y;
  float s = *sp, wmin = *wminp;
  const float* xr = x + (size_t)b * IN_DIM;
  const int* wrow = qw + (size_t)o * IN_DIM;
  float acc = 0.f;
  for (int k = 0; k < IN_DIM; ++k)
    acc += xr[k] * fmaf((float)wrow[k] + 32768.0f, s, wmin);
  out[(size_t)b * OUT_DIM + o] =
      acc + fmaf((float)qb[o] + 32768.0f, *bsp, *bminp);
}

// ---------------- launch ----------------
extern "C" void kernel_launch(void* const* d_in, const int* in_sizes, int n_in,
                              void* d_out, int out_size, void* d_ws,
                              size_t ws_size, hipStream_t stream) {
  const float* x      = (const float*)d_in[0];
  const int*   qw     = (const int*)d_in[1];
  const int*   qb     = (const int*)d_in[2];
  const float* scale  = (const float*)d_in[3];
  const float* wmin   = (const float*)d_in[4];
  const float* bscale = (const float*)d_in[5];
  const float* bmin   = (const float*)d_in[6];
  float* out = (float*)d_out;

  const size_t xb_bytes = (size_t)B_DIM * IN_DIM * 2;      // 64 MiB
  const size_t wb_bytes = (size_t)OUT_DIM * IN_DIM * 2;    // 32 MiB
  const size_t bias_bytes = (size_t)OUT_DIM * 4;

  if (ws_size < xb_bytes + wb_bytes + bias_bytes) {
    naive_ql_kernel<<<dim3(OUT_DIM / 256, B_DIM), 256, 0, stream>>>(
        x, qw, qb, scale, wmin, bscale, bmin, out);
    return;
  }

  uint16_t* Xb    = (uint16_t*)d_ws;
  uint16_t* Wb    = (uint16_t*)((char*)d_ws + xb_bytes);
  float*    biasf = (float*)((char*)d_ws + xb_bytes + wb_bytes);

  cvt_x_kernel<<<(B_DIM * (size_t)IN_DIM / 8 + 255) / 256, 256, 0, stream>>>(x, Xb);
  cvt_w_kernel<<<(OUT_DIM * (size_t)IN_DIM / 8 + 255) / 256, 256, 0, stream>>>(
      qw, Wb, scale, wmin);
  cvt_bias_kernel<<<(OUT_DIM + 255) / 256, 256, 0, stream>>>(qb, biasf, bscale,
                                                             bmin);

  gemm256_kernel<<<512, 512, 0, stream>>>(Xb, Wb, biasf, out);
}

// Round 4
// 320.049 us; speedup vs baseline: 1.1489x; 1.0840x over previous
//
#include <hip/hip_runtime.h>
#include <cstdint>
#include <cstddef>

// ---------------------------------------------------------------------------
// QuantizedLinear: out = x @ W^T + bias (affine-dequant int16-range weights)
// B=8192, IN=4096, OUT=4096. Dequant to bf16 in ws; 256x256 MFMA GEMM,
// 8 waves, 4 K-half LDS slots, chunk-XOR LDS swizzle (R3, conflicts=0).
// R4: software-pipelined ds_reads (pre-read next phase's fragments, counted
// lgkmcnt(4/8), never 0) + vmcnt(4) checkpoints. Phases = (mf-half, K-half).
// ---------------------------------------------------------------------------

#define B_DIM  8192
#define IN_DIM 4096
#define OUT_DIM 4096

typedef short    bf16x8 __attribute__((ext_vector_type(8)));
typedef float    f32x4  __attribute__((ext_vector_type(4)));
typedef uint16_t u16x8  __attribute__((ext_vector_type(8)));

__device__ __forceinline__ uint16_t f2bf(float f) {
  uint32_t u = __builtin_bit_cast(uint32_t, f);
  u += 0x7FFFu + ((u >> 16) & 1u);
  return (uint16_t)(u >> 16);
}

__device__ __forceinline__ void gload_lds16(const void* g, void* l) {
  __builtin_amdgcn_global_load_lds(
      (const __attribute__((address_space(1))) unsigned int*)g,
      (__attribute__((address_space(3))) unsigned int*)l,
      16, 0, 0);
}

// ---------------- prologue: conversions ----------------

__global__ void cvt_x_kernel(const float* __restrict__ x,
                             uint16_t* __restrict__ o) {
  size_t i = (size_t)blockIdx.x * blockDim.x + threadIdx.x;
  const float4* xv = (const float4*)x;
  float4 a = xv[i * 2], b = xv[i * 2 + 1];
  u16x8 r;
  r[0] = f2bf(a.x); r[1] = f2bf(a.y); r[2] = f2bf(a.z); r[3] = f2bf(a.w);
  r[4] = f2bf(b.x); r[5] = f2bf(b.y); r[6] = f2bf(b.z); r[7] = f2bf(b.w);
  ((u16x8*)o)[i] = r;
}

__global__ void cvt_w_kernel(const int* __restrict__ q,
                             uint16_t* __restrict__ o,
                             const float* __restrict__ sp,
                             const float* __restrict__ wminp) {
  size_t i = (size_t)blockIdx.x * blockDim.x + threadIdx.x;
  float s = *sp, wmin = *wminp;
  const int4* qv = (const int4*)q;
  int4 a = qv[i * 2], b = qv[i * 2 + 1];
  u16x8 r;
  r[0] = f2bf(fmaf((float)a.x + 32768.0f, s, wmin));
  r[1] = f2bf(fmaf((float)a.y + 32768.0f, s, wmin));
  r[2] = f2bf(fmaf((float)a.z + 32768.0f, s, wmin));
  r[3] = f2bf(fmaf((float)a.w + 32768.0f, s, wmin));
  r[4] = f2bf(fmaf((float)b.x + 32768.0f, s, wmin));
  r[5] = f2bf(fmaf((float)b.y + 32768.0f, s, wmin));
  r[6] = f2bf(fmaf((float)b.z + 32768.0f, s, wmin));
  r[7] = f2bf(fmaf((float)b.w + 32768.0f, s, wmin));
  ((u16x8*)o)[i] = r;
}

__global__ void cvt_bias_kernel(const int* __restrict__ qb,
                                float* __restrict__ o,
                                const float* __restrict__ bsp,
                                const float* __restrict__ bminp) {
  int i = blockIdx.x * blockDim.x + threadIdx.x;
  if (i < OUT_DIM)
    o[i] = fmaf((float)qb[i] + 32768.0f, *bsp, *bminp);
}

// ---------------- main GEMM ----------------
// Phases per iter t (K-halves 2t, 2t+1 in slots s0=(2t)&3, s1=(2t+1)&3):
//  p0: mf 0-3 x slot s0   (A0,B0)   pre-read A1<-s0 a[4..7]        stage Ga.j0
//  p1: mf 4-7 x slot s0   (A1,B0)   pre-read A0,B1<-s1             stage Ga.j1  vmcnt(4)
//  p2: mf 0-3 x slot s1   (A0,B1)   pre-read A1<-s1 a[4..7]        stage Gb.j0
//  p3: mf 4-7 x slot s1   (A1,B1)   pre-read A0,B0<-slot((2t+2)&3) stage Gb.j1  vmcnt(4)
// Each phase waits lgkmcnt(own batch: 4 or 8) after its barrier -> previous
// phase's batch complete, own batch stays in flight. vmcnt(4) ledger:
//  - t.p1 pre-read of s1 (half 2t+1, staged t-1.p0/p1): confirmed at t-1.p3
//    vmcnt(4) (newest 4 = t-1.p2/p3 issues).
//  - t.p3 pre-read of half 2t+2 (staged t-1.p2/p3): confirmed at t.p1 vmcnt(4).
//  - WAR: stage into a slot always >=1 barrier after the slot's last ds_read
//    batch is lgkm-confirmed (checked per phase).

__global__ __launch_bounds__(512, 2) void gemm256_kernel(
    const uint16_t* __restrict__ A, const uint16_t* __restrict__ Bw,
    const float* __restrict__ bias, float* __restrict__ C) {
  __shared__ bf16x8 Asl[4][1024];  // 4 x 16 KiB
  __shared__ bf16x8 Bsl[4][1024];  // 4 x 16 KiB

  const int tid  = threadIdx.x;
  const int wave = tid >> 6;
  const int lane = tid & 63;

  int bid = blockIdx.x;
  int swz = (bid & 7) * 64 + (bid >> 3);   // bijective, nwg=512
  const int bm = swz >> 4;
  const int bn = swz & 15;
  const int M0 = bm * 256, N0 = bn * 256;

  const int wm = wave >> 2, wn = wave & 3;
  const int l15 = lane & 15, l4 = lane >> 4;
  const int swk = l4 ^ ((l15 >> 1) & 3);          // read-side chunk swizzle
  const int aIdx = (wm * 128 + l15) * 4 + swk;    // + 64*r for A-frag row r
  const int bIdx = (wn * 64 + l15) * 4 + swk;     // + 64*n for B-frag col n

  const int schunk = (lane & 3) ^ ((lane >> 3) & 3);  // source-side swizzle
  const uint16_t* aSrc =
      A + (size_t)(M0 + wave * 16 + (lane >> 2)) * IN_DIM + schunk * 8;
  const uint16_t* bSrc =
      Bw + (size_t)(N0 + wave * 16 + (lane >> 2)) * IN_DIM + schunk * 8;

  f32x4 acc[8][4];
#pragma unroll
  for (int i = 0; i < 8; ++i)
#pragma unroll
    for (int j = 0; j < 4; ++j) acc[i][j] = (f32x4){0.f, 0.f, 0.f, 0.f};

#define STAGE_A(G, j)                                                       \
  gload_lds16(aSrc + (size_t)(j) * 128 * IN_DIM + (size_t)(G) * 32,         \
              (char*)&Asl[(G) & 3][0] + (j) * 8192 + wave * 1024)
#define STAGE_B(G, j)                                                       \
  gload_lds16(bSrc + (size_t)(j) * 128 * IN_DIM + (size_t)(G) * 32,         \
              (char*)&Bsl[(G) & 3][0] + (j) * 8192 + wave * 1024)

  // prologue: stage halves 0,1,2; vmcnt(4) => halves 0 AND 1 landed
  for (int G = 0; G < 3; ++G) {
    STAGE_A(G, 0); STAGE_A(G, 1); STAGE_B(G, 0); STAGE_B(G, 1);
  }
  asm volatile("s_waitcnt vmcnt(4)" ::: "memory");
  __builtin_amdgcn_s_barrier();
  __builtin_amdgcn_sched_barrier(0);

  bf16x8 A0[4], A1[4], B0[4], B1[4];
  // preload phase-0 operands from slot 0 (8 reads; p0 waits lgkmcnt(4))
#pragma unroll
  for (int i = 0; i < 4; ++i) A0[i] = Asl[0][aIdx + 64 * i];
#pragma unroll
  for (int n = 0; n < 4; ++n) B0[n] = Bsl[0][bIdx + 64 * n];

  for (int t = 0; t < 64; ++t) {
    const int s0 = (2 * t) & 3, s1 = (2 * t + 1) & 3, s0n = (2 * t + 2) & 3;
    const int Ga = 2 * t + 3, Gb = 2 * t + 4;
    const bool pa = (Ga < 128), pb = (Gb < 128);

    // ---- p0: mf 0-3 x s0 (A0,B0); pre-read A1<-s0 hi; stage Ga.j0
    {
#pragma unroll
      for (int i = 0; i < 4; ++i) A1[i] = Asl[s0][aIdx + 64 * (4 + i)];
      if (pa) { STAGE_A(Ga, 0); STAGE_B(Ga, 0); }
      __builtin_amdgcn_s_barrier();
      asm volatile("s_waitcnt lgkmcnt(4)" ::: "memory");
      __builtin_amdgcn_sched_barrier(0);
      __builtin_amdgcn_s_setprio(1);
#pragma unroll
      for (int i = 0; i < 4; ++i)
#pragma unroll
        for (int n = 0; n < 4; ++n)
          acc[i][n] = __builtin_amdgcn_mfma_f32_16x16x32_bf16(A0[i], B0[n], acc[i][n], 0, 0, 0);
      __builtin_amdgcn_s_setprio(0);
      __builtin_amdgcn_s_barrier();
      __builtin_amdgcn_sched_barrier(0);
    }
    // ---- p1: mf 4-7 x s0 (A1,B0); pre-read A0,B1<-s1; stage Ga.j1; vmcnt(4)
    {
#pragma unroll
      for (int i = 0; i < 4; ++i) A0[i] = Asl[s1][aIdx + 64 * i];
#pragma unroll
      for (int n = 0; n < 4; ++n) B1[n] = Bsl[s1][bIdx + 64 * n];
      if (pa) { STAGE_A(Ga, 1); STAGE_B(Ga, 1); }
      __builtin_amdgcn_s_barrier();
      asm volatile("s_waitcnt lgkmcnt(8)" ::: "memory");
      __builtin_amdgcn_sched_barrier(0);
      __builtin_amdgcn_s_setprio(1);
#pragma unroll
      for (int i = 0; i < 4; ++i)
#pragma unroll
        for (int n = 0; n < 4; ++n)
          acc[4 + i][n] = __builtin_amdgcn_mfma_f32_16x16x32_bf16(A1[i], B0[n], acc[4 + i][n], 0, 0, 0);
      __builtin_amdgcn_s_setprio(0);
      asm volatile("s_waitcnt vmcnt(4)" ::: "memory");
      __builtin_amdgcn_s_barrier();
      __builtin_amdgcn_sched_barrier(0);
    }
    // ---- p2: mf 0-3 x s1 (A0,B1); pre-read A1<-s1 hi; stage Gb.j0
    {
#pragma unroll
      for (int i = 0; i < 4; ++i) A1[i] = Asl[s1][aIdx + 64 * (4 + i)];
      if (pb) { STAGE_A(Gb, 0); STAGE_B(Gb, 0); }
      __builtin_amdgcn_s_barrier();
      asm volatile("s_waitcnt lgkmcnt(4)" ::: "memory");
      __builtin_amdgcn_sched_barrier(0);
      __builtin_amdgcn_s_setprio(1);
#pragma unroll
      for (int i = 0; i < 4; ++i)
#pragma unroll
        for (int n = 0; n < 4; ++n)
          acc[i][n] = __builtin_amdgcn_mfma_f32_16x16x32_bf16(A0[i], B1[n], acc[i][n], 0, 0, 0);
      __builtin_amdgcn_s_setprio(0);
      __builtin_amdgcn_s_barrier();
      __builtin_amdgcn_sched_barrier(0);
    }
    // ---- p3: mf 4-7 x s1 (A1,B1); pre-read A0,B0<-s0n; stage Gb.j1; vmcnt(4)
    {
#pragma unroll
      for (int i = 0; i < 4; ++i) A0[i] = Asl[s0n][aIdx + 64 * i];
#pragma unroll
      for (int n = 0; n < 4; ++n) B0[n] = Bsl[s0n][bIdx + 64 * n];
      if (pb) { STAGE_A(Gb, 1); STAGE_B(Gb, 1); }
      __builtin_amdgcn_s_barrier();
      asm volatile("s_waitcnt lgkmcnt(8)" ::: "memory");
      __builtin_amdgcn_sched_barrier(0);
      __builtin_amdgcn_s_setprio(1);
#pragma unroll
      for (int i = 0; i < 4; ++i)
#pragma unroll
        for (int n = 0; n < 4; ++n)
          acc[4 + i][n] = __builtin_amdgcn_mfma_f32_16x16x32_bf16(A1[i], B1[n], acc[4 + i][n], 0, 0, 0);
      __builtin_amdgcn_s_setprio(0);
      asm volatile("s_waitcnt vmcnt(4)" ::: "memory");
      __builtin_amdgcn_s_barrier();
      __builtin_amdgcn_sched_barrier(0);
    }
  }
#undef STAGE_A
#undef STAGE_B

  // epilogue: C/D frag layout col=lane&15, row=(lane>>4)*4+j
  const int ccol = N0 + wn * 64 + l15;
#pragma unroll
  for (int nf = 0; nf < 4; ++nf) {
    float bv = bias[ccol + nf * 16];
#pragma unroll
    for (int mf = 0; mf < 8; ++mf) {
      const int r0 = M0 + wm * 128 + mf * 16 + l4 * 4;
#pragma unroll
      for (int j = 0; j < 4; ++j)
        C[(size_t)(r0 + j) * OUT_DIM + ccol + nf * 16] = acc[mf][nf][j] + bv;
    }
  }
}

// ---------------- naive fallback (only if ws too small) ----------------
__global__ void naive_ql_kernel(const float* __restrict__ x,
                                const int* __restrict__ qw,
                                const int* __restrict__ qb,
                                const float* sp, const float* wminp,
                                const float* bsp, const float* bminp,
                                float* __restrict__ out) {
  int o = blockIdx.x * blockDim.x + threadIdx.x;
  int b = blockIdx.y;
  float s = *sp, wmin = *wminp;
  const float* xr = x + (size_t)b * IN_DIM;
  const int* wrow = qw + (size_t)o * IN_DIM;
  float acc = 0.f;
  for (int k = 0; k < IN_DIM; ++k)
    acc += xr[k] * fmaf((float)wrow[k] + 32768.0f, s, wmin);
  out[(size_t)b * OUT_DIM + o] =
      acc + fmaf((float)qb[o] + 32768.0f, *bsp, *bminp);
}

// ---------------- launch ----------------
extern "C" void kernel_launch(void* const* d_in, const int* in_sizes, int n_in,
                              void* d_out, int out_size, void* d_ws,
                              size_t ws_size, hipStream_t stream) {
  const float* x      = (const float*)d_in[0];
  const int*   qw     = (const int*)d_in[1];
  const int*   qb     = (const int*)d_in[2];
  const float* scale  = (const float*)d_in[3];
  const float* wmin   = (const float*)d_in[4];
  const float* bscale = (const float*)d_in[5];
  const float* bmin   = (const float*)d_in[6];
  float* out = (float*)d_out;

  const size_t xb_bytes = (size_t)B_DIM * IN_DIM * 2;
  const size_t wb_bytes = (size_t)OUT_DIM * IN_DIM * 2;
  const size_t bias_bytes = (size_t)OUT_DIM * 4;

  if (ws_size < xb_bytes + wb_bytes + bias_bytes) {
    naive_ql_kernel<<<dim3(OUT_DIM / 256, B_DIM), 256, 0, stream>>>(
        x, qw, qb, scale, wmin, bscale, bmin, out);
    return;
  }

  uint16_t* Xb    = (uint16_t*)d_ws;
  uint16_t* Wb    = (uint16_t*)((char*)d_ws + xb_bytes);
  float*    biasf = (float*)((char*)d_ws + xb_bytes + wb_bytes);

  cvt_x_kernel<<<(B_DIM * (size_t)IN_DIM / 8 + 255) / 256, 256, 0, stream>>>(x, Xb);
  cvt_w_kernel<<<(OUT_DIM * (size_t)IN_DIM / 8 + 255) / 256, 256, 0, stream>>>(
      qw, Wb, scale, wmin);
  cvt_bias_kernel<<<(OUT_DIM + 255) / 256, 256, 0, stream>>>(qb, biasf, bscale,
                                                             bmin);

  gemm256_kernel<<<512, 512, 0, stream>>>(Xb, Wb, biasf, out);
}